// Round 1
// baseline (6199.081 us; speedup 1.0000x reference)
//
#include <hip/hip_runtime.h>

#define HID 128
#define NL 3

// ---------------------------------------------------------------------------
// GEMM: Y[r][:] = X[r][:] @ W (+bias), K=N=128. 128-row tile per block.
// Block = 256 threads (4 waves). Each wave: 32 rows x 128 cols.
// Lane -> colgroup cg = lane&31 (4 cols), rowgroup rg = lane>>5 (16 rows each).
// LDS: X tile 64KB + W 64KB = 128KB -> 1 block/CU.
// ---------------------------------------------------------------------------
template<bool BIAS>
__global__ __launch_bounds__(256) void gemm128_kernel(
    const float* __restrict__ X, const float* __restrict__ W,
    const float* __restrict__ bias, float* __restrict__ Y, int nrows)
{
  __shared__ float Xs[128 * HID];
  __shared__ float Ws[HID * HID];
  const int tid = threadIdx.x;
  const long row0 = (long)blockIdx.x * 128;

  // stage W (4096 float4, contiguous)
  #pragma unroll
  for (int i = 0; i < 16; ++i) {
    int f = tid + i * 256;
    ((float4*)Ws)[f] = ((const float4*)W)[f];
  }
  // stage X tile (rows beyond nrows -> zeros)
  #pragma unroll
  for (int i = 0; i < 16; ++i) {
    int f = tid + i * 256;
    int r = f >> 5, c4 = f & 31;
    long gr = row0 + r;
    float4 v = make_float4(0.f, 0.f, 0.f, 0.f);
    if (gr < nrows) v = ((const float4*)X)[gr * 32 + c4];
    ((float4*)Xs)[f] = v;
  }
  __syncthreads();

  const int lane = tid & 63;
  const int wave = tid >> 6;
  const int cg = lane & 31;
  const int rg = lane >> 5;
  const int rbase = wave * 32 + rg * 16;
  const int c0 = cg * 4;

  float acc[16][4];
  #pragma unroll
  for (int r = 0; r < 16; ++r)
    #pragma unroll
    for (int c = 0; c < 4; ++c) acc[r][c] = 0.f;

  #pragma unroll 2
  for (int k = 0; k < HID; k += 4) {
    float4 w0 = *(const float4*)&Ws[(k + 0) * HID + c0];
    float4 w1 = *(const float4*)&Ws[(k + 1) * HID + c0];
    float4 w2 = *(const float4*)&Ws[(k + 2) * HID + c0];
    float4 w3 = *(const float4*)&Ws[(k + 3) * HID + c0];
    #pragma unroll
    for (int r = 0; r < 16; ++r) {
      float4 xv = *(const float4*)&Xs[(rbase + r) * HID + k];
      acc[r][0] = fmaf(xv.x, w0.x, acc[r][0]);
      acc[r][0] = fmaf(xv.y, w1.x, acc[r][0]);
      acc[r][0] = fmaf(xv.z, w2.x, acc[r][0]);
      acc[r][0] = fmaf(xv.w, w3.x, acc[r][0]);
      acc[r][1] = fmaf(xv.x, w0.y, acc[r][1]);
      acc[r][1] = fmaf(xv.y, w1.y, acc[r][1]);
      acc[r][1] = fmaf(xv.z, w2.y, acc[r][1]);
      acc[r][1] = fmaf(xv.w, w3.y, acc[r][1]);
      acc[r][2] = fmaf(xv.x, w0.z, acc[r][2]);
      acc[r][2] = fmaf(xv.y, w1.z, acc[r][2]);
      acc[r][2] = fmaf(xv.z, w2.z, acc[r][2]);
      acc[r][2] = fmaf(xv.w, w3.z, acc[r][2]);
      acc[r][3] = fmaf(xv.x, w0.w, acc[r][3]);
      acc[r][3] = fmaf(xv.y, w1.w, acc[r][3]);
      acc[r][3] = fmaf(xv.z, w2.w, acc[r][3]);
      acc[r][3] = fmaf(xv.w, w3.w, acc[r][3]);
    }
  }

  float4 bv = make_float4(0.f, 0.f, 0.f, 0.f);
  if (BIAS) bv = *(const float4*)&bias[c0];

  #pragma unroll
  for (int r = 0; r < 16; ++r) {
    long gr = row0 + rbase + r;
    if (gr < nrows) {
      float4 o;
      o.x = acc[r][0] + bv.x;
      o.y = acc[r][1] + bv.y;
      o.z = acc[r][2] + bv.z;
      o.w = acc[r][3] + bv.w;
      *(float4*)&Y[gr * HID + c0] = o;
    }
  }
}

// ---------------------------------------------------------------------------
// Fused edge pipeline: ew = edge_attr @ gcn_ew[i]; msgs = ew * h[src];
// agg[dst] += msgs  (fp32 atomics).
// Same GEMM body, different epilogue.
// ---------------------------------------------------------------------------
__global__ __launch_bounds__(256) void edge_gemm_scatter_kernel(
    const float* __restrict__ EA, const float* __restrict__ W,
    const float* __restrict__ H, const int* __restrict__ src,
    const int* __restrict__ dst, float* __restrict__ agg, int nE)
{
  __shared__ float Xs[128 * HID];
  __shared__ float Ws[HID * HID];
  const int tid = threadIdx.x;
  const long row0 = (long)blockIdx.x * 128;

  #pragma unroll
  for (int i = 0; i < 16; ++i) {
    int f = tid + i * 256;
    ((float4*)Ws)[f] = ((const float4*)W)[f];
  }
  #pragma unroll
  for (int i = 0; i < 16; ++i) {
    int f = tid + i * 256;
    int r = f >> 5, c4 = f & 31;
    long gr = row0 + r;
    float4 v = make_float4(0.f, 0.f, 0.f, 0.f);
    if (gr < nE) v = ((const float4*)EA)[gr * 32 + c4];
    ((float4*)Xs)[f] = v;
  }
  __syncthreads();

  const int lane = tid & 63;
  const int wave = tid >> 6;
  const int cg = lane & 31;
  const int rg = lane >> 5;
  const int rbase = wave * 32 + rg * 16;
  const int c0 = cg * 4;

  float acc[16][4];
  #pragma unroll
  for (int r = 0; r < 16; ++r)
    #pragma unroll
    for (int c = 0; c < 4; ++c) acc[r][c] = 0.f;

  #pragma unroll 2
  for (int k = 0; k < HID; k += 4) {
    float4 w0 = *(const float4*)&Ws[(k + 0) * HID + c0];
    float4 w1 = *(const float4*)&Ws[(k + 1) * HID + c0];
    float4 w2 = *(const float4*)&Ws[(k + 2) * HID + c0];
    float4 w3 = *(const float4*)&Ws[(k + 3) * HID + c0];
    #pragma unroll
    for (int r = 0; r < 16; ++r) {
      float4 xv = *(const float4*)&Xs[(rbase + r) * HID + k];
      acc[r][0] = fmaf(xv.x, w0.x, acc[r][0]);
      acc[r][0] = fmaf(xv.y, w1.x, acc[r][0]);
      acc[r][0] = fmaf(xv.z, w2.x, acc[r][0]);
      acc[r][0] = fmaf(xv.w, w3.x, acc[r][0]);
      acc[r][1] = fmaf(xv.x, w0.y, acc[r][1]);
      acc[r][1] = fmaf(xv.y, w1.y, acc[r][1]);
      acc[r][1] = fmaf(xv.z, w2.y, acc[r][1]);
      acc[r][1] = fmaf(xv.w, w3.y, acc[r][1]);
      acc[r][2] = fmaf(xv.x, w0.z, acc[r][2]);
      acc[r][2] = fmaf(xv.y, w1.z, acc[r][2]);
      acc[r][2] = fmaf(xv.z, w2.z, acc[r][2]);
      acc[r][2] = fmaf(xv.w, w3.z, acc[r][2]);
      acc[r][3] = fmaf(xv.x, w0.w, acc[r][3]);
      acc[r][3] = fmaf(xv.y, w1.w, acc[r][3]);
      acc[r][3] = fmaf(xv.z, w2.w, acc[r][3]);
      acc[r][3] = fmaf(xv.w, w3.w, acc[r][3]);
    }
  }

  #pragma unroll
  for (int r = 0; r < 16; ++r) {
    long e = row0 + rbase + r;
    if (e < nE) {
      int s = src[e];
      int d = dst[e];
      float4 hv = *(const float4*)&H[(long)s * HID + c0];
      float* ap = &agg[(long)d * HID + c0];
      atomicAdd(ap + 0, acc[r][0] * hv.x);
      atomicAdd(ap + 1, acc[r][1] * hv.y);
      atomicAdd(ap + 2, acc[r][2] * hv.z);
      atomicAdd(ap + 3, acc[r][3] * hv.w);
    }
  }
}

// ---------------------------------------------------------------------------
// Per-node: v = relu(agg + b) [+ residual]; out = LN(v)*scale + bias
// One wave per node, lane holds 2 floats.
// ---------------------------------------------------------------------------
__global__ __launch_bounds__(256) void ln_kernel(
    const float* __restrict__ agg, const float* __restrict__ b,
    const float* __restrict__ res, const float* __restrict__ lnS,
    const float* __restrict__ lnB, float* __restrict__ out, int n)
{
  const int wave = threadIdx.x >> 6;
  const int lane = threadIdx.x & 63;
  const long node = (long)blockIdx.x * 4 + wave;
  if (node >= n) return;

  float2 v = *(const float2*)&agg[node * HID + lane * 2];
  float2 bb = *(const float2*)&b[lane * 2];
  v.x += bb.x; v.y += bb.y;
  v.x = fmaxf(v.x, 0.f); v.y = fmaxf(v.y, 0.f);
  if (res != nullptr) {
    float2 rr = *(const float2*)&res[node * HID + lane * 2];
    v.x += rr.x; v.y += rr.y;
  }
  float s = v.x + v.y;
  #pragma unroll
  for (int off = 32; off >= 1; off >>= 1) s += __shfl_xor(s, off);
  float mean = s * (1.f / 128.f);
  float dx = v.x - mean, dy = v.y - mean;
  float q = dx * dx + dy * dy;
  #pragma unroll
  for (int off = 32; off >= 1; off >>= 1) q += __shfl_xor(q, off);
  float rstd = rsqrtf(q * (1.f / 128.f) + 1e-5f);
  float2 sc = *(const float2*)&lnS[lane * 2];
  float2 sb = *(const float2*)&lnB[lane * 2];
  float2 o;
  o.x = dx * rstd * sc.x + sb.x;
  o.y = dy * rstd * sc.y + sb.y;
  *(float2*)&out[node * HID + lane * 2] = o;
}

// ---------------------------------------------------------------------------
// Pooling
// ---------------------------------------------------------------------------
__global__ void count_kernel(const int* __restrict__ batch, int n,
                             int* __restrict__ counts)
{
  int i = blockIdx.x * 256 + threadIdx.x;
  if (i < n) atomicAdd(&counts[batch[i]], 1);
}

__global__ __launch_bounds__(128) void pool_kernel(
    const float* __restrict__ X, const int* __restrict__ batch, int n,
    float* __restrict__ sums)
{
  const int col = threadIdx.x;
  long n0 = (long)blockIdx.x * 1024;
  long n1 = n0 + 1024; if (n1 > n) n1 = n;
  if (n0 >= n) return;
  float s = 0.f;
  int g = batch[n0];
  for (long i = n0; i < n1; ++i) {
    int gi = batch[i];
    if (gi != g) {
      atomicAdd(&sums[g * HID + col], s);
      s = 0.f;
      g = gi;
    }
    s += X[i * HID + col];
  }
  atomicAdd(&sums[g * HID + col], s);
}

__global__ void finalize_kernel(const float* __restrict__ sums,
                                const int* __restrict__ counts,
                                float* __restrict__ out, int total)
{
  int i = blockIdx.x * 256 + threadIdx.x;
  if (i < total) {
    int g = i >> 7;
    float c = (float)counts[g];
    out[i] = sums[i] / fmaxf(c, 1.f);
  }
}

// ---------------------------------------------------------------------------
extern "C" void kernel_launch(void* const* d_in, const int* in_sizes, int n_in,
                              void* d_out, int out_size, void* d_ws, size_t ws_size,
                              hipStream_t stream)
{
  const float* nf    = (const float*)d_in[0];
  const float* ea    = (const float*)d_in[1];
  const float* ipw   = (const float*)d_in[2];
  const float* ipb   = (const float*)d_in[3];
  const float* gw    = (const float*)d_in[4];
  const float* gew   = (const float*)d_in[5];
  const float* gb    = (const float*)d_in[6];
  const float* lns   = (const float*)d_in[7];
  const float* lnb   = (const float*)d_in[8];
  const float* opw   = (const float*)d_in[9];
  const float* opb   = (const float*)d_in[10];
  const int*   ei    = (const int*)d_in[11];
  const int*   batch = (const int*)d_in[12];
  float* out = (float*)d_out;

  const int N = 100000;
  const int E = 800000;
  const int G = 64;
  const int* srcI = ei;
  const int* dstI = ei + E;

  char* ws = (char*)d_ws;
  const size_t nodeBytes = (size_t)N * HID * sizeof(float);
  float* bufA = (float*)(ws);
  float* bufB = (float*)(ws + nodeBytes);
  float* bufC = (float*)(ws + 2 * nodeBytes);
  float* sums = (float*)(ws + 3 * nodeBytes);
  int*   counts = (int*)(ws + 3 * nodeBytes + (size_t)G * HID * sizeof(float));

  dim3 blk(256);
  const int gemmBlocksN = (N + 127) / 128;
  const int gemmBlocksE = (E + 127) / 128;

  // x = node_features @ in_proj_w + in_proj_b   -> bufA
  gemm128_kernel<true><<<gemmBlocksN, blk, 0, stream>>>(nf, ipw, ipb, bufA, N);

  float* x = bufA;
  float* h = bufB;
  for (int i = 0; i < NL; ++i) {
    // h = x @ gcn_w[i]
    gemm128_kernel<false><<<gemmBlocksN, blk, 0, stream>>>(
        x, gw + (size_t)i * HID * HID, nullptr, h, N);
    // agg = 0
    hipMemsetAsync(bufC, 0, nodeBytes, stream);
    // agg[dst] += (edge_attr @ gcn_ew[i]) * h[src]
    edge_gemm_scatter_kernel<<<gemmBlocksE, blk, 0, stream>>>(
        ea, gew + (size_t)i * HID * HID, h, srcI, dstI, bufC, E);
    // x_new = LN(relu(agg + b) [+ x]) -> overwrite h buffer, then swap
    ln_kernel<<<(N + 3) / 4, blk, 0, stream>>>(
        bufC, gb + i * HID, (i > 0) ? x : nullptr, lns + i * HID, lnb + i * HID,
        h, N);
    float* t = x; x = h; h = t;
  }

  // y = x @ out_proj_w + out_proj_b -> h
  gemm128_kernel<true><<<gemmBlocksN, blk, 0, stream>>>(x, opw, opb, h, N);

  // pooling
  hipMemsetAsync(sums, 0, (size_t)G * HID * sizeof(float) + G * sizeof(int),
                 stream);
  count_kernel<<<(N + 255) / 256, blk, 0, stream>>>(batch, N, counts);
  pool_kernel<<<(N + 1023) / 1024, dim3(128), 0, stream>>>(h, batch, N, sums);
  finalize_kernel<<<(G * HID + 255) / 256, blk, 0, stream>>>(
      sums, counts, out, G * HID);
}

// Round 2
// 2457.723 us; speedup vs baseline: 2.5223x; 2.5223x over previous
//
#include <hip/hip_runtime.h>

#define HID 128

typedef __attribute__((ext_vector_type(8))) short bf16x8;
typedef __attribute__((ext_vector_type(4))) float f32x4;

__device__ __forceinline__ unsigned short f2bf(float f) {
  union { float f; unsigned u; } v; v.f = f;
  return (unsigned short)((v.u + 0x7FFFu + ((v.u >> 16) & 1u)) >> 16);
}

// ---------------------------------------------------------------------------
// Register-blocked MFMA GEMM, no LDS. Block=256thr=4 waves; wave = 32 rows x
// 128 cols; A frags per-wave-private (fp32->bf16 in-register or bf16 direct),
// B = Wt [N][K] bf16 row-major, streamed from L2 per k-step.
// mfma_f32_16x16x32_bf16: A[lane&15][(lane>>4)*8+j], B: col=lane&15, same k.
// D[(lane>>4)*4+r][lane&15].
// ---------------------------------------------------------------------------
template<bool SRCF32, bool BIAS, bool OUTBF16>
__global__ __launch_bounds__(256, 3) void gemm_node_kernel(
    const void* __restrict__ Xv, const unsigned short* __restrict__ Wt,
    const float* __restrict__ bias, float* __restrict__ Yf,
    unsigned short* __restrict__ Yb, int nrows)
{
  const int tid  = threadIdx.x;
  const int lane = tid & 63;
  const int wave = tid >> 6;
  const int lr = lane & 15;   // row-in-tile (A) / col-in-tile (B,D)
  const int lg = lane >> 4;   // k-group
  const long row0 = (long)blockIdx.x * 128 + wave * 32;

  // ---- load A fragments (2 row-tiles x 4 k-steps) ----
  bf16x8 A[2][4];
  #pragma unroll
  for (int rt = 0; rt < 2; ++rt) {
    long R = row0 + rt * 16 + lr;
    if (R >= nrows) R = nrows - 1;
    if (SRCF32) {
      const float* xp = (const float*)Xv + R * HID;
      #pragma unroll
      for (int ks = 0; ks < 4; ++ks) {
        float4 lo = *(const float4*)(xp + ks * 32 + lg * 8);
        float4 hi = *(const float4*)(xp + ks * 32 + lg * 8 + 4);
        bf16x8 a;
        a[0] = (short)f2bf(lo.x); a[1] = (short)f2bf(lo.y);
        a[2] = (short)f2bf(lo.z); a[3] = (short)f2bf(lo.w);
        a[4] = (short)f2bf(hi.x); a[5] = (short)f2bf(hi.y);
        a[6] = (short)f2bf(hi.z); a[7] = (short)f2bf(hi.w);
        A[rt][ks] = a;
      }
    } else {
      const unsigned short* xp = (const unsigned short*)Xv + R * HID;
      #pragma unroll
      for (int ks = 0; ks < 4; ++ks)
        A[rt][ks] = *(const bf16x8*)(xp + ks * 32 + lg * 8);
    }
  }

  f32x4 acc[2][8];
  #pragma unroll
  for (int rt = 0; rt < 2; ++rt)
    #pragma unroll
    for (int ct = 0; ct < 8; ++ct)
      acc[rt][ct] = (f32x4){0.f, 0.f, 0.f, 0.f};

  #pragma unroll
  for (int ks = 0; ks < 4; ++ks) {
    bf16x8 Bf[8];
    #pragma unroll
    for (int ct = 0; ct < 8; ++ct)
      Bf[ct] = *(const bf16x8*)(Wt + (ct * 16 + lr) * HID + ks * 32 + lg * 8);
    #pragma unroll
    for (int rt = 0; rt < 2; ++rt)
      #pragma unroll
      for (int ct = 0; ct < 8; ++ct)
        acc[rt][ct] = __builtin_amdgcn_mfma_f32_16x16x32_bf16(
            A[rt][ks], Bf[ct], acc[rt][ct], 0, 0, 0);
  }

  // ---- epilogue ----
  #pragma unroll
  for (int rt = 0; rt < 2; ++rt) {
    #pragma unroll
    for (int r = 0; r < 4; ++r) {
      long e = row0 + rt * 16 + lg * 4 + r;
      if (e < nrows) {
        #pragma unroll
        for (int ct = 0; ct < 8; ++ct) {
          int col = ct * 16 + lr;
          float v = acc[rt][ct][r];
          if (BIAS) v += bias[col];
          if (OUTBF16) Yb[e * HID + col] = f2bf(v);
          else         Yf[e * HID + col] = v;
        }
      }
    }
  }
}

// ---------------------------------------------------------------------------
// Fused edge pipeline: ew = bf16(edge_attr) @ Wt^T (MFMA), then per edge
// msg = ew * h[src], agg[dst] += msg via fp32 atomics.
// ---------------------------------------------------------------------------
__global__ __launch_bounds__(256, 3) void gemm_edge_kernel(
    const float* __restrict__ EA, const unsigned short* __restrict__ Wt,
    const float* __restrict__ H, const int* __restrict__ src,
    const int* __restrict__ dst, float* __restrict__ agg, int nE)
{
  const int tid  = threadIdx.x;
  const int lane = tid & 63;
  const int wave = tid >> 6;
  const int lr = lane & 15;
  const int lg = lane >> 4;
  const long row0 = (long)blockIdx.x * 128 + wave * 32;

  bf16x8 A[2][4];
  #pragma unroll
  for (int rt = 0; rt < 2; ++rt) {
    long R = row0 + rt * 16 + lr;
    const float* xp = EA + R * HID;
    #pragma unroll
    for (int ks = 0; ks < 4; ++ks) {
      float4 lo = *(const float4*)(xp + ks * 32 + lg * 8);
      float4 hi = *(const float4*)(xp + ks * 32 + lg * 8 + 4);
      bf16x8 a;
      a[0] = (short)f2bf(lo.x); a[1] = (short)f2bf(lo.y);
      a[2] = (short)f2bf(lo.z); a[3] = (short)f2bf(lo.w);
      a[4] = (short)f2bf(hi.x); a[5] = (short)f2bf(hi.y);
      a[6] = (short)f2bf(hi.z); a[7] = (short)f2bf(hi.w);
      A[rt][ks] = a;
    }
  }

  f32x4 acc[2][8];
  #pragma unroll
  for (int rt = 0; rt < 2; ++rt)
    #pragma unroll
    for (int ct = 0; ct < 8; ++ct)
      acc[rt][ct] = (f32x4){0.f, 0.f, 0.f, 0.f};

  #pragma unroll
  for (int ks = 0; ks < 4; ++ks) {
    bf16x8 Bf[8];
    #pragma unroll
    for (int ct = 0; ct < 8; ++ct)
      Bf[ct] = *(const bf16x8*)(Wt + (ct * 16 + lr) * HID + ks * 32 + lg * 8);
    #pragma unroll
    for (int rt = 0; rt < 2; ++rt)
      #pragma unroll
      for (int ct = 0; ct < 8; ++ct)
        acc[rt][ct] = __builtin_amdgcn_mfma_f32_16x16x32_bf16(
            A[rt][ks], Bf[ct], acc[rt][ct], 0, 0, 0);
  }

  // ---- gather / gate / scatter epilogue ----
  #pragma unroll
  for (int rt = 0; rt < 2; ++rt) {
    #pragma unroll
    for (int r = 0; r < 4; ++r) {
      long e = row0 + rt * 16 + lg * 4 + r;
      int s = src[e];
      int d = dst[e];
      const float* hp = H + (long)s * HID + lr;
      float* ap = agg + (long)d * HID + lr;
      #pragma unroll
      for (int ct = 0; ct < 8; ++ct) {
        float m = acc[rt][ct][r] * hp[ct * 16];
        atomicAdd(ap + ct * 16, m);
      }
    }
  }
}

// ---------------------------------------------------------------------------
// Weight prep: transpose + fp32->bf16. wt[m][n][k] = bf16(W_m[k][n]).
// m: 0=ipw, 1..3=gcn_w, 4..6=gcn_ew, 7=opw.
// ---------------------------------------------------------------------------
__global__ __launch_bounds__(256) void prep_w_kernel(
    const float* __restrict__ ipw, const float* __restrict__ gw,
    const float* __restrict__ gew, const float* __restrict__ opw,
    unsigned short* __restrict__ wt)
{
  int idx = blockIdx.x * 1024 + threadIdx.x * 4;
  #pragma unroll
  for (int t = 0; t < 4; ++t) {
    int i = idx + t;
    int m = i >> 14, r = i & 16383;
    int n = r >> 7, k = r & 127;
    const float* srcm;
    if (m == 0)      srcm = ipw;
    else if (m <= 3) srcm = gw  + (size_t)(m - 1) * 16384;
    else if (m <= 6) srcm = gew + (size_t)(m - 4) * 16384;
    else             srcm = opw;
    wt[i] = f2bf(srcm[k * HID + n]);
  }
}

// ---------------------------------------------------------------------------
// Per-node: v = relu(agg + b) [+ residual]; x = LN(v); writes fp32 + bf16.
// One wave per node. res may alias xf (read-before-write per thread).
// ---------------------------------------------------------------------------
__global__ __launch_bounds__(256) void ln_kernel(
    const float* __restrict__ agg, const float* __restrict__ b,
    const float* res, const float* __restrict__ lnS,
    const float* __restrict__ lnB, float* xf, unsigned short* __restrict__ xb,
    int n)
{
  const int wave = threadIdx.x >> 6;
  const int lane = threadIdx.x & 63;
  const long node = (long)blockIdx.x * 4 + wave;
  if (node >= n) return;

  float2 v = *(const float2*)&agg[node * HID + lane * 2];
  float2 bb = *(const float2*)&b[lane * 2];
  v.x += bb.x; v.y += bb.y;
  v.x = fmaxf(v.x, 0.f); v.y = fmaxf(v.y, 0.f);
  if (res != nullptr) {
    float2 rr = *(const float2*)&res[node * HID + lane * 2];
    v.x += rr.x; v.y += rr.y;
  }
  float s = v.x + v.y;
  #pragma unroll
  for (int off = 32; off >= 1; off >>= 1) s += __shfl_xor(s, off);
  float mean = s * (1.f / 128.f);
  float dx = v.x - mean, dy = v.y - mean;
  float q = dx * dx + dy * dy;
  #pragma unroll
  for (int off = 32; off >= 1; off >>= 1) q += __shfl_xor(q, off);
  float rstd = rsqrtf(q * (1.f / 128.f) + 1e-5f);
  float2 sc = *(const float2*)&lnS[lane * 2];
  float2 sb = *(const float2*)&lnB[lane * 2];
  float ox = dx * rstd * sc.x + sb.x;
  float oy = dy * rstd * sc.y + sb.y;
  *(float2*)&xf[node * HID + lane * 2] = make_float2(ox, oy);
  unsigned pk = (unsigned)f2bf(ox) | ((unsigned)f2bf(oy) << 16);
  *(unsigned*)&xb[node * HID + lane * 2] = pk;
}

// ---------------------------------------------------------------------------
// Pooling
// ---------------------------------------------------------------------------
__global__ void count_kernel(const int* __restrict__ batch, int n,
                             int* __restrict__ counts)
{
  int i = blockIdx.x * 256 + threadIdx.x;
  if (i < n) atomicAdd(&counts[batch[i]], 1);
}

__global__ __launch_bounds__(128) void pool_kernel(
    const float* __restrict__ X, const int* __restrict__ batch, int n,
    float* __restrict__ sums)
{
  const int col = threadIdx.x;
  long n0 = (long)blockIdx.x * 1024;
  long n1 = n0 + 1024; if (n1 > n) n1 = n;
  if (n0 >= n) return;
  float s = 0.f;
  int g = batch[n0];
  for (long i = n0; i < n1; ++i) {
    int gi = batch[i];
    if (gi != g) {
      atomicAdd(&sums[g * HID + col], s);
      s = 0.f;
      g = gi;
    }
    s += X[i * HID + col];
  }
  atomicAdd(&sums[g * HID + col], s);
}

__global__ void finalize_kernel(const float* __restrict__ sums,
                                const int* __restrict__ counts,
                                float* __restrict__ out, int total)
{
  int i = blockIdx.x * 256 + threadIdx.x;
  if (i < total) {
    int g = i >> 7;
    float c = (float)counts[g];
    out[i] = sums[i] / fmaxf(c, 1.f);
  }
}

// ---------------------------------------------------------------------------
extern "C" void kernel_launch(void* const* d_in, const int* in_sizes, int n_in,
                              void* d_out, int out_size, void* d_ws, size_t ws_size,
                              hipStream_t stream)
{
  const float* nf    = (const float*)d_in[0];
  const float* ea    = (const float*)d_in[1];
  const float* ipw   = (const float*)d_in[2];
  const float* ipb   = (const float*)d_in[3];
  const float* gw    = (const float*)d_in[4];
  const float* gew   = (const float*)d_in[5];
  const float* gb    = (const float*)d_in[6];
  const float* lns   = (const float*)d_in[7];
  const float* lnb   = (const float*)d_in[8];
  const float* opw   = (const float*)d_in[9];
  const float* opb   = (const float*)d_in[10];
  const int*   ei    = (const int*)d_in[11];
  const int*   batch = (const int*)d_in[12];
  float* out = (float*)d_out;

  const int N = 100000;
  const int E = 800000;
  const int G = 64;
  const int* srcI = ei;
  const int* dstI = ei + E;

  char* ws = (char*)d_ws;
  const size_t nodeF = (size_t)N * HID * sizeof(float);       // 51.2 MB
  const size_t nodeB = (size_t)N * HID * sizeof(unsigned short); // 25.6 MB
  float*          xf   = (float*)(ws);
  float*          h    = (float*)(ws + nodeF);
  float*          agg  = (float*)(ws + 2 * nodeF);
  unsigned short* xb   = (unsigned short*)(ws + 3 * nodeF);
  unsigned short* wt   = (unsigned short*)(ws + 3 * nodeF + nodeB);
  float*          sums = (float*)(ws + 3 * nodeF + nodeB + 8 * 16384 * 2);
  int*            cnts = (int*)((char*)sums + (size_t)G * HID * sizeof(float));

  dim3 blk(256);
  const int nBlkN = (N + 127) / 128;   // 782
  const int nBlkE = (E + 127) / 128;   // 6250

  // weights -> transposed bf16
  prep_w_kernel<<<128, blk, 0, stream>>>(ipw, gw, gew, opw, wt);

  // x0 = bf16(nf @ ipw + ipb)
  gemm_node_kernel<true, true, true><<<nBlkN, blk, 0, stream>>>(
      nf, wt, ipb, nullptr, xb, N);

  for (int i = 0; i < 3; ++i) {
    // h = x @ gcn_w[i]  (fp32 out)
    gemm_node_kernel<false, false, false><<<nBlkN, blk, 0, stream>>>(
        xb, wt + (size_t)(1 + i) * 16384, nullptr, h, nullptr, N);
    // agg = 0
    hipMemsetAsync(agg, 0, nodeF, stream);
    // agg[dst] += (ea @ gcn_ew[i]) * h[src]
    gemm_edge_kernel<<<nBlkE, blk, 0, stream>>>(
        ea, wt + (size_t)(4 + i) * 16384, h, srcI, dstI, agg, E);
    // x = LN(relu(agg+b) [+x]) -> xf (fp32) + xb (bf16)
    ln_kernel<<<(N + 3) / 4, blk, 0, stream>>>(
        agg, gb + i * HID, (i > 0) ? xf : nullptr, lns + i * HID,
        lnb + i * HID, xf, xb, N);
  }

  // y = x @ out_proj_w + out_proj_b -> h (fp32)
  gemm_node_kernel<false, true, false><<<nBlkN, blk, 0, stream>>>(
      xb, wt + (size_t)7 * 16384, opb, h, nullptr, N);

  // pooling
  hipMemsetAsync(sums, 0, (size_t)G * HID * sizeof(float) + G * sizeof(int),
                 stream);
  count_kernel<<<(N + 255) / 256, blk, 0, stream>>>(batch, N, cnts);
  pool_kernel<<<(N + 1023) / 1024, dim3(128), 0, stream>>>(h, batch, N, sums);
  finalize_kernel<<<(G * HID + 255) / 256, blk, 0, stream>>>(
      sums, cnts, out, G * HID);
}

// Round 3
// 1290.845 us; speedup vs baseline: 4.8023x; 1.9040x over previous
//
#include <hip/hip_runtime.h>

#define HID 128

typedef __attribute__((ext_vector_type(8))) short bf16x8;
typedef __attribute__((ext_vector_type(4))) float f32x4;

__device__ __forceinline__ unsigned short f2bf(float f) {
  union { float f; unsigned u; } v; v.f = f;
  return (unsigned short)((v.u + 0x7FFFu + ((v.u >> 16) & 1u)) >> 16);
}

// ---------------------------------------------------------------------------
// Register-blocked MFMA GEMM, no LDS. Block=256thr=4 waves; wave = 32 rows x
// 128 cols. B = Wt [N][K] bf16 row-major, streamed from L2 per k-step.
// ---------------------------------------------------------------------------
template<bool SRCF32, bool BIAS, bool OUTBF16>
__global__ __launch_bounds__(256, 3) void gemm_node_kernel(
    const void* __restrict__ Xv, const unsigned short* __restrict__ Wt,
    const float* __restrict__ bias, float* __restrict__ Yf,
    unsigned short* __restrict__ Yb, int nrows)
{
  const int tid  = threadIdx.x;
  const int lane = tid & 63;
  const int wave = tid >> 6;
  const int lr = lane & 15;
  const int lg = lane >> 4;
  const long row0 = (long)blockIdx.x * 128 + wave * 32;

  bf16x8 A[2][4];
  #pragma unroll
  for (int rt = 0; rt < 2; ++rt) {
    long R = row0 + rt * 16 + lr;
    if (R >= nrows) R = nrows - 1;
    if (SRCF32) {
      const float* xp = (const float*)Xv + R * HID;
      #pragma unroll
      for (int ks = 0; ks < 4; ++ks) {
        float4 lo = *(const float4*)(xp + ks * 32 + lg * 8);
        float4 hi = *(const float4*)(xp + ks * 32 + lg * 8 + 4);
        bf16x8 a;
        a[0] = (short)f2bf(lo.x); a[1] = (short)f2bf(lo.y);
        a[2] = (short)f2bf(lo.z); a[3] = (short)f2bf(lo.w);
        a[4] = (short)f2bf(hi.x); a[5] = (short)f2bf(hi.y);
        a[6] = (short)f2bf(hi.z); a[7] = (short)f2bf(hi.w);
        A[rt][ks] = a;
      }
    } else {
      const unsigned short* xp = (const unsigned short*)Xv + R * HID;
      #pragma unroll
      for (int ks = 0; ks < 4; ++ks)
        A[rt][ks] = *(const bf16x8*)(xp + ks * 32 + lg * 8);
    }
  }

  f32x4 acc[2][8];
  #pragma unroll
  for (int rt = 0; rt < 2; ++rt)
    #pragma unroll
    for (int ct = 0; ct < 8; ++ct)
      acc[rt][ct] = (f32x4){0.f, 0.f, 0.f, 0.f};

  #pragma unroll
  for (int ks = 0; ks < 4; ++ks) {
    bf16x8 Bf[8];
    #pragma unroll
    for (int ct = 0; ct < 8; ++ct)
      Bf[ct] = *(const bf16x8*)(Wt + (ct * 16 + lr) * HID + ks * 32 + lg * 8);
    #pragma unroll
    for (int rt = 0; rt < 2; ++rt)
      #pragma unroll
      for (int ct = 0; ct < 8; ++ct)
        acc[rt][ct] = __builtin_amdgcn_mfma_f32_16x16x32_bf16(
            A[rt][ks], Bf[ct], acc[rt][ct], 0, 0, 0);
  }

  #pragma unroll
  for (int rt = 0; rt < 2; ++rt) {
    #pragma unroll
    for (int r = 0; r < 4; ++r) {
      long e = row0 + rt * 16 + lg * 4 + r;
      if (e < nrows) {
        #pragma unroll
        for (int ct = 0; ct < 8; ++ct) {
          int col = ct * 16 + lr;
          float v = acc[rt][ct][r];
          if (BIAS) v += bias[col];
          if (OUTBF16) Yb[e * HID + col] = f2bf(v);
          else         Yf[e * HID + col] = v;
        }
      }
    }
  }
}

// ---------------------------------------------------------------------------
// Edge pipeline over dst-sorted slots: ew = bf16(EA[perm[slot]]) @ Wt^T,
// msg = ew * h[ssrc[slot]], agg[sdst[slot]] += msg with in-lane run
// compression (consecutive slots in a lane share dst -> one atomic per run).
// E % 128 == 0, so no row guards needed.
// ---------------------------------------------------------------------------
__global__ __launch_bounds__(256, 3) void gemm_edge_kernel(
    const float* __restrict__ EA, const unsigned short* __restrict__ Wt,
    const float* __restrict__ H, const int* __restrict__ perm,
    const int* __restrict__ ssrc, const int* __restrict__ sdst,
    float* __restrict__ agg, int nE)
{
  const int tid  = threadIdx.x;
  const int lane = tid & 63;
  const int wave = tid >> 6;
  const int lr = lane & 15;
  const int lg = lane >> 4;
  const long row0 = (long)blockIdx.x * 128 + wave * 32;

  bf16x8 A[2][4];
  #pragma unroll
  for (int rt = 0; rt < 2; ++rt) {
    long R = row0 + rt * 16 + lr;
    const float* xp = EA + (long)perm[R] * HID;
    #pragma unroll
    for (int ks = 0; ks < 4; ++ks) {
      float4 lo = *(const float4*)(xp + ks * 32 + lg * 8);
      float4 hi = *(const float4*)(xp + ks * 32 + lg * 8 + 4);
      bf16x8 a;
      a[0] = (short)f2bf(lo.x); a[1] = (short)f2bf(lo.y);
      a[2] = (short)f2bf(lo.z); a[3] = (short)f2bf(lo.w);
      a[4] = (short)f2bf(hi.x); a[5] = (short)f2bf(hi.y);
      a[6] = (short)f2bf(hi.z); a[7] = (short)f2bf(hi.w);
      A[rt][ks] = a;
    }
  }

  f32x4 acc[2][8];
  #pragma unroll
  for (int rt = 0; rt < 2; ++rt)
    #pragma unroll
    for (int ct = 0; ct < 8; ++ct)
      acc[rt][ct] = (f32x4){0.f, 0.f, 0.f, 0.f};

  #pragma unroll
  for (int ks = 0; ks < 4; ++ks) {
    bf16x8 Bf[8];
    #pragma unroll
    for (int ct = 0; ct < 8; ++ct)
      Bf[ct] = *(const bf16x8*)(Wt + (ct * 16 + lr) * HID + ks * 32 + lg * 8);
    #pragma unroll
    for (int rt = 0; rt < 2; ++rt)
      #pragma unroll
      for (int ct = 0; ct < 8; ++ct)
        acc[rt][ct] = __builtin_amdgcn_mfma_f32_16x16x32_bf16(
            A[rt][ks], Bf[ct], acc[rt][ct], 0, 0, 0);
  }

  // ---- gather / gate / compressed scatter ----
  #pragma unroll
  for (int rt = 0; rt < 2; ++rt) {
    const long base = row0 + rt * 16 + lg * 4;
    float am[8];
    int dprev = -1;
    #pragma unroll
    for (int r = 0; r < 4; ++r) {
      long slot = base + r;
      int s = ssrc[slot];
      int d = sdst[slot];
      const float* hp = H + (long)s * HID + lr;
      float m[8];
      #pragma unroll
      for (int ct = 0; ct < 8; ++ct) m[ct] = acc[rt][ct][r] * hp[ct * 16];
      bool same = (d == dprev);
      if (!same && dprev >= 0) {
        float* ap = agg + (long)dprev * HID + lr;
        #pragma unroll
        for (int ct = 0; ct < 8; ++ct) atomicAdd(ap + ct * 16, am[ct]);
      }
      #pragma unroll
      for (int ct = 0; ct < 8; ++ct) am[ct] = same ? am[ct] + m[ct] : m[ct];
      dprev = d;
    }
    float* ap = agg + (long)dprev * HID + lr;
    #pragma unroll
    for (int ct = 0; ct < 8; ++ct) atomicAdd(ap + ct * 16, am[ct]);
  }
}

// ---------------------------------------------------------------------------
// Counting sort of edges by dst: hist -> 2-level exclusive scan -> scatter.
// ---------------------------------------------------------------------------
__global__ void hist_kernel(const int* __restrict__ dst, int nE,
                            int* __restrict__ hist)
{
  int i = blockIdx.x * 256 + threadIdx.x;
  if (i < nE) atomicAdd(&hist[dst[i]], 1);
}

__global__ __launch_bounds__(256) void scan1_kernel(
    const int* __restrict__ hist, int n, int* __restrict__ partial)
{
  __shared__ int buf[256];
  int t = threadIdx.x;
  int i = blockIdx.x * 256 + t;
  buf[t] = (i < n) ? hist[i] : 0;
  __syncthreads();
  #pragma unroll
  for (int off = 128; off >= 1; off >>= 1) {
    if (t < off) buf[t] += buf[t + off];
    __syncthreads();
  }
  if (t == 0) partial[blockIdx.x] = buf[0];
}

__global__ __launch_bounds__(512) void scan2_kernel(int* __restrict__ partial,
                                                    int nb)
{
  __shared__ int buf[512];
  int t = threadIdx.x;
  buf[t] = (t < nb) ? partial[t] : 0;
  __syncthreads();
  for (int off = 1; off < 512; off <<= 1) {
    int v = (t >= off) ? buf[t - off] : 0;
    __syncthreads();
    buf[t] += v;
    __syncthreads();
  }
  if (t < nb) partial[t] = (t == 0) ? 0 : buf[t - 1];
}

__global__ __launch_bounds__(256) void scan3_kernel(
    const int* __restrict__ hist, const int* __restrict__ partial,
    int* __restrict__ cursor, int n)
{
  __shared__ int buf[256];
  int t = threadIdx.x;
  int i = blockIdx.x * 256 + t;
  int v = (i < n) ? hist[i] : 0;
  buf[t] = v;
  __syncthreads();
  for (int off = 1; off < 256; off <<= 1) {
    int w = (t >= off) ? buf[t - off] : 0;
    __syncthreads();
    buf[t] += w;
    __syncthreads();
  }
  if (i < n) cursor[i] = partial[blockIdx.x] + buf[t] - v;
}

__global__ void scatter_kernel(const int* __restrict__ src,
                               const int* __restrict__ dst, int nE,
                               int* __restrict__ cursor,
                               int* __restrict__ perm,
                               int* __restrict__ ssrc, int* __restrict__ sdst)
{
  int e = blockIdx.x * 256 + threadIdx.x;
  if (e < nE) {
    int d = dst[e];
    int pos = atomicAdd(&cursor[d], 1);
    perm[pos] = e;
    ssrc[pos] = src[e];
    sdst[pos] = d;
  }
}

// ---------------------------------------------------------------------------
// Weight prep: wt[m][n][k] = bf16(W_m[k][n]).
// ---------------------------------------------------------------------------
__global__ __launch_bounds__(256) void prep_w_kernel(
    const float* __restrict__ ipw, const float* __restrict__ gw,
    const float* __restrict__ gew, const float* __restrict__ opw,
    unsigned short* __restrict__ wt)
{
  int idx = blockIdx.x * 1024 + threadIdx.x * 4;
  #pragma unroll
  for (int t = 0; t < 4; ++t) {
    int i = idx + t;
    int m = i >> 14, r = i & 16383;
    int n = r >> 7, k = r & 127;
    const float* srcm;
    if (m == 0)      srcm = ipw;
    else if (m <= 3) srcm = gw  + (size_t)(m - 1) * 16384;
    else if (m <= 6) srcm = gew + (size_t)(m - 4) * 16384;
    else             srcm = opw;
    wt[i] = f2bf(srcm[k * HID + n]);
  }
}

// ---------------------------------------------------------------------------
// Per-node: v = relu(agg + b) [+ residual]; x = LN(v); writes fp32 + bf16.
// ---------------------------------------------------------------------------
__global__ __launch_bounds__(256) void ln_kernel(
    const float* __restrict__ agg, const float* __restrict__ b,
    const float* res, const float* __restrict__ lnS,
    const float* __restrict__ lnB, float* xf, unsigned short* __restrict__ xb,
    int n)
{
  const int wave = threadIdx.x >> 6;
  const int lane = threadIdx.x & 63;
  const long node = (long)blockIdx.x * 4 + wave;
  if (node >= n) return;

  float2 v = *(const float2*)&agg[node * HID + lane * 2];
  float2 bb = *(const float2*)&b[lane * 2];
  v.x += bb.x; v.y += bb.y;
  v.x = fmaxf(v.x, 0.f); v.y = fmaxf(v.y, 0.f);
  if (res != nullptr) {
    float2 rr = *(const float2*)&res[node * HID + lane * 2];
    v.x += rr.x; v.y += rr.y;
  }
  float s = v.x + v.y;
  #pragma unroll
  for (int off = 32; off >= 1; off >>= 1) s += __shfl_xor(s, off);
  float mean = s * (1.f / 128.f);
  float dx = v.x - mean, dy = v.y - mean;
  float q = dx * dx + dy * dy;
  #pragma unroll
  for (int off = 32; off >= 1; off >>= 1) q += __shfl_xor(q, off);
  float rstd = rsqrtf(q * (1.f / 128.f) + 1e-5f);
  float2 sc = *(const float2*)&lnS[lane * 2];
  float2 sb = *(const float2*)&lnB[lane * 2];
  float ox = dx * rstd * sc.x + sb.x;
  float oy = dy * rstd * sc.y + sb.y;
  *(float2*)&xf[node * HID + lane * 2] = make_float2(ox, oy);
  unsigned pk = (unsigned)f2bf(ox) | ((unsigned)f2bf(oy) << 16);
  *(unsigned*)&xb[node * HID + lane * 2] = pk;
}

// ---------------------------------------------------------------------------
// Pooling: batch is sorted -> counts via binary search; sums via chunked
// run-accumulate + boundary atomics.
// ---------------------------------------------------------------------------
__global__ void graph_count_kernel(const int* __restrict__ batch, int n,
                                   int nG, int* __restrict__ counts)
{
  int g = threadIdx.x;
  if (g >= nG) return;
  int lo0 = 0, hi0 = n;
  while (lo0 < hi0) { int mid = (lo0 + hi0) >> 1; if (batch[mid] < g) lo0 = mid + 1; else hi0 = mid; }
  int lo1 = lo0, hi1 = n;
  while (lo1 < hi1) { int mid = (lo1 + hi1) >> 1; if (batch[mid] < g + 1) lo1 = mid + 1; else hi1 = mid; }
  counts[g] = lo1 - lo0;
}

__global__ __launch_bounds__(128) void pool_kernel(
    const float* __restrict__ X, const int* __restrict__ batch, int n,
    float* __restrict__ sums)
{
  const int col = threadIdx.x;
  long n0 = (long)blockIdx.x * 64;
  long n1 = n0 + 64; if (n1 > n) n1 = n;
  if (n0 >= n) return;
  float s = 0.f;
  int g = batch[n0];
  for (long i = n0; i < n1; ++i) {
    int gi = batch[i];
    if (gi != g) {
      atomicAdd(&sums[g * HID + col], s);
      s = 0.f;
      g = gi;
    }
    s += X[i * HID + col];
  }
  atomicAdd(&sums[g * HID + col], s);
}

__global__ void finalize_kernel(const float* __restrict__ sums,
                                const int* __restrict__ counts,
                                float* __restrict__ out, int total)
{
  int i = blockIdx.x * 256 + threadIdx.x;
  if (i < total) {
    int g = i >> 7;
    float c = (float)counts[g];
    out[i] = sums[i] / fmaxf(c, 1.f);
  }
}

// ---------------------------------------------------------------------------
extern "C" void kernel_launch(void* const* d_in, const int* in_sizes, int n_in,
                              void* d_out, int out_size, void* d_ws, size_t ws_size,
                              hipStream_t stream)
{
  const float* nf    = (const float*)d_in[0];
  const float* ea    = (const float*)d_in[1];
  const float* ipw   = (const float*)d_in[2];
  const float* ipb   = (const float*)d_in[3];
  const float* gw    = (const float*)d_in[4];
  const float* gew   = (const float*)d_in[5];
  const float* gb    = (const float*)d_in[6];
  const float* lns   = (const float*)d_in[7];
  const float* lnb   = (const float*)d_in[8];
  const float* opw   = (const float*)d_in[9];
  const float* opb   = (const float*)d_in[10];
  const int*   ei    = (const int*)d_in[11];
  const int*   batch = (const int*)d_in[12];
  float* out = (float*)d_out;

  const int N = 100000;
  const int E = 800000;
  const int G = 64;
  const int* srcI = ei;
  const int* dstI = ei + E;

  char* ws = (char*)d_ws;
  const size_t nodeF = (size_t)N * HID * sizeof(float);          // 51.2 MB
  const size_t nodeB = (size_t)N * HID * sizeof(unsigned short); // 25.6 MB
  size_t off = 0;
  float*          xf   = (float*)(ws + off); off += nodeF;
  float*          h    = (float*)(ws + off); off += nodeF;
  float*          agg  = (float*)(ws + off); off += nodeF;
  unsigned short* xb   = (unsigned short*)(ws + off); off += nodeB;
  unsigned short* wt   = (unsigned short*)(ws + off); off += 8 * 16384 * 2;
  int*            perm = (int*)(ws + off); off += (size_t)E * 4;
  int*            ssrc = (int*)(ws + off); off += (size_t)E * 4;
  int*            sdst = (int*)(ws + off); off += (size_t)E * 4;
  int*            hist = (int*)(ws + off); off += (size_t)N * 4;
  int*            curs = (int*)(ws + off); off += (size_t)N * 4;
  int*            part = (int*)(ws + off); off += 512 * 4;
  float*          sums = (float*)(ws + off); off += (size_t)G * HID * 4;
  int*            cnts = (int*)(ws + off); off += G * 4;

  dim3 blk(256);
  const int nBlkN = (N + 127) / 128;   // 782
  const int nBlkE = E / 128;           // 6250
  const int nBins = (N + 255) / 256;   // 391

  // weights -> transposed bf16
  prep_w_kernel<<<128, blk, 0, stream>>>(ipw, gw, gew, opw, wt);

  // counting sort of edges by dst
  hipMemsetAsync(hist, 0, (size_t)N * 4, stream);
  hist_kernel<<<(E + 255) / 256, blk, 0, stream>>>(dstI, E, hist);
  scan1_kernel<<<nBins, blk, 0, stream>>>(hist, N, part);
  scan2_kernel<<<1, dim3(512), 0, stream>>>(part, nBins);
  scan3_kernel<<<nBins, blk, 0, stream>>>(hist, part, curs, N);
  scatter_kernel<<<(E + 255) / 256, blk, 0, stream>>>(srcI, dstI, E, curs,
                                                      perm, ssrc, sdst);

  // x0 = bf16(nf @ ipw + ipb)
  gemm_node_kernel<true, true, true><<<nBlkN, blk, 0, stream>>>(
      nf, wt, ipb, nullptr, xb, N);

  for (int i = 0; i < 3; ++i) {
    gemm_node_kernel<false, false, false><<<nBlkN, blk, 0, stream>>>(
        xb, wt + (size_t)(1 + i) * 16384, nullptr, h, nullptr, N);
    hipMemsetAsync(agg, 0, nodeF, stream);
    gemm_edge_kernel<<<nBlkE, blk, 0, stream>>>(
        ea, wt + (size_t)(4 + i) * 16384, h, perm, ssrc, sdst, agg, E);
    ln_kernel<<<(N + 3) / 4, blk, 0, stream>>>(
        agg, gb + i * HID, (i > 0) ? xf : nullptr, lns + i * HID,
        lnb + i * HID, xf, xb, N);
  }

  // y = x @ out_proj_w + out_proj_b -> h (fp32)
  gemm_node_kernel<false, true, false><<<nBlkN, blk, 0, stream>>>(
      xb, wt + (size_t)7 * 16384, opb, h, nullptr, N);

  // pooling
  graph_count_kernel<<<1, dim3(64), 0, stream>>>(batch, N, G, cnts);
  hipMemsetAsync(sums, 0, (size_t)G * HID * 4, stream);
  pool_kernel<<<(N + 63) / 64, dim3(128), 0, stream>>>(h, batch, N, sums);
  finalize_kernel<<<(G * HID + 255) / 256, blk, 0, stream>>>(
      sums, cnts, out, G * HID);
}